// Round 5
// baseline (3465.608 us; speedup 1.0000x reference)
//
#include <hip/hip_runtime.h>

// Residual VQ on MI355X (gfx950).
// z: [8, 32768, 32] f32; codebooks: [10, 512, 32] f32.
// Outputs (flat f32 in d_out): quantized [B,N,D], indices [B,N,Q] (as float),
// commit_loss [Q] (zeros).
//
// R5 = R4 structure (codebook resident in VGPRs, 8 codewords/lane, one wave
// per 256 points, shfl_xor argmin butterfly with lower-index tie-break,
// replay kernel for bit-exact quantized) + explicit VGPR pinning:
// R4's VGPR_Count=156 proved the compiler rematerialized the codeword loads
// inside the point loop (back to L1-broadcast-bound, VALUBusy 36%). Empty
// asm volatile("" : "+v"(x)) on each codebook float makes the loaded value
// unrecreatable, forcing true register residency (~390 VGPR < 512 at 1
// wave/SIMD).
// Distance arithmetic bit-identical to R1 (absmax 0.0): 8-accumulator j&7
// dot, dist = fma(-2,dot,rr)+cc, strict-< first-min argmin.

#define RVQ_B 8
#define RVQ_N 32768
#define RVQ_D 32
#define RVQ_Q 10
#define RVQ_C 512

static constexpr int  NPTS     = RVQ_B * RVQ_N;             // 262144
static constexpr long IDX_OFF  = (long)NPTS * RVQ_D;        // 8388608
static constexpr long LOSS_OFF = IDX_OFF + (long)NPTS * RVQ_Q;
static constexpr int  NWAVES   = 1024;                      // 1 per SIMD
static constexpr int  PPW      = NPTS / NWAVES;             // 256 points/wave

// ---------------------------------------------------------------------------
// Kernel 1: per-codeword squared norms -> ws[Q*C] (bit-exact numpy tree)
__global__ void rvq_cb_norms(const float* __restrict__ cb, float* __restrict__ ws) {
    int i = blockIdx.x * blockDim.x + threadIdx.x;
    if (i >= RVQ_Q * RVQ_C) return;
    const float* c = cb + (long)i * RVQ_D;
    float a[8];
#pragma unroll
    for (int j = 0; j < 8; ++j) a[j] = c[j] * c[j];
#pragma unroll
    for (int j = 8; j < RVQ_D; ++j) a[j & 7] = fmaf(c[j], c[j], a[j & 7]);
    ws[i] = ((a[0] + a[1]) + (a[2] + a[3])) + ((a[4] + a[5]) + (a[6] + a[7]));
}

// ---------------------------------------------------------------------------
// Kernel 2: one VQ stage. Block = 64 (one wave). Each lane owns candidates
// [lane*8, lane*8+8). rin = residual in (z for q==0), rout = residual out.
__global__ __launch_bounds__(64, 1) void rvq_stage(const float* __restrict__ rin,
                                                   float* __restrict__ rout,
                                                   const float* __restrict__ cb,
                                                   const float* __restrict__ cbn,
                                                   float* __restrict__ idx_out,
                                                   int q) {
    const int  lane  = threadIdx.x;          // 0..63 (block == 1 wave)
    const long pbase = (long)blockIdx.x * PPW;

    // ---- codebook slice into registers: 8 codewords/lane, PINNED in VGPRs
    float cw[8][RVQ_D];
    {
        const float4* cbase = (const float4*)(cb + ((long)q * RVQ_C + lane * 8) * RVQ_D);
#pragma unroll
        for (int j = 0; j < 8; ++j)
#pragma unroll
            for (int w = 0; w < 8; ++w) {
                const float4 v = cbase[j * 8 + w];
                cw[j][w * 4 + 0] = v.x; cw[j][w * 4 + 1] = v.y;
                cw[j][w * 4 + 2] = v.z; cw[j][w * 4 + 3] = v.w;
            }
    }
    float cc[8];
#pragma unroll
    for (int j = 0; j < 8; ++j) cc[j] = cbn[q * RVQ_C + lane * 8 + j];

    // Pin: make each loaded value opaque so the compiler CANNOT re-load it
    // from global inside the point loop (R4 failure mode).
#pragma unroll
    for (int j = 0; j < 8; ++j) {
#pragma unroll
        for (int d = 0; d < RVQ_D; ++d) asm volatile("" : "+v"(cw[j][d]));
        asm volatile("" : "+v"(cc[j]));
    }

    const float4* rin4 = (const float4*)rin;

    // distance+argmin for one point (residual identical across lanes).
    // Bit-identical tree to R1.
    auto process = [&](const float4 (&rb4)[8]) -> int {
        float rb[RVQ_D];
#pragma unroll
        for (int w = 0; w < 8; ++w) {
            rb[w * 4 + 0] = rb4[w].x; rb[w * 4 + 1] = rb4[w].y;
            rb[w * 4 + 2] = rb4[w].z; rb[w * 4 + 3] = rb4[w].w;
        }
        float a[8];
#pragma unroll
        for (int j = 0; j < 8; ++j) a[j] = rb[j] * rb[j];
#pragma unroll
        for (int j = 8; j < RVQ_D; ++j) a[j & 7] = fmaf(rb[j], rb[j], a[j & 7]);
        const float rr = ((a[0] + a[1]) + (a[2] + a[3])) + ((a[4] + a[5]) + (a[6] + a[7]));

        float bd = __builtin_inff();
        int   bj = 0;
#pragma unroll
        for (int j = 0; j < 8; ++j) {
            float acc[8];
#pragma unroll
            for (int d = 0; d < 8; ++d) acc[d] = rb[d] * cw[j][d];
#pragma unroll
            for (int d = 8; d < RVQ_D; ++d) acc[d & 7] = fmaf(rb[d], cw[j][d], acc[d & 7]);
            const float dot = ((acc[0] + acc[1]) + (acc[2] + acc[3])) +
                              ((acc[4] + acc[5]) + (acc[6] + acc[7]));
            const float dist = fmaf(-2.0f, dot, rr) + cc[j];
            if (dist < bd) { bd = dist; bj = j; }   // first-min within lane
        }
        int bi = lane * 8 + bj;
#pragma unroll
        for (int m = 1; m <= 32; m <<= 1) {
            const float od = __shfl_xor(bd, m, 64);
            const int   oi = __shfl_xor(bi, m, 64);
            if (od < bd || (od == bd && oi < bi)) { bd = od; bi = oi; }
        }
        return bi;   // uniform across the wave
    };

    const int dlane = lane & 31;
    // finish a deferred residual update: bit-exact reference chain
    auto finish = [&](long p, float rl, float cwl) {
        const float t   = cwl - rl;
        const float qst = rl + t;
        const float rn  = rl - qst;
        if (lane < 32) rout[p * RVQ_D + lane] = rn;
    };

    float4 rbA[8], rbB[8];
#pragma unroll
    for (int w = 0; w < 8; ++w) rbA[w] = rin4[pbase * 8 + w];

    long  pPend = 0; float rlPend = 0.0f, cwPend = 0.0f;

#pragma unroll 1
    for (int i = 0; i < PPW; i += 2) {
        const long p0 = pbase + i, p1 = p0 + 1;

        // prefetch residual of p1 (latency hides under p0 compute)
#pragma unroll
        for (int w = 0; w < 8; ++w) rbB[w] = rin4[p1 * 8 + w];

        const int bi0 = process(rbA);
        if (lane == 0) idx_out[p0 * RVQ_Q + q] = (float)bi0;
        const float rl0 = rin[p0 * RVQ_D + dlane];
        const float cw0 = cb[((long)q * RVQ_C + bi0) * RVQ_D + dlane];
        if (i > 0) finish(pPend, rlPend, cwPend);

        if (i + 2 < PPW) {
#pragma unroll
            for (int w = 0; w < 8; ++w) rbA[w] = rin4[(p0 + 2) * 8 + w];
        }

        const int bi1 = process(rbB);
        if (lane == 0) idx_out[p1 * RVQ_Q + q] = (float)bi1;
        const float rl1 = rin[p1 * RVQ_D + dlane];
        const float cw1 = cb[((long)q * RVQ_C + bi1) * RVQ_D + dlane];
        finish(p0, rl0, cw0);

        pPend = p1; rlPend = rl1; cwPend = cw1;
    }
    finish(pPend, rlPend, cwPend);
}

// ---------------------------------------------------------------------------
// Kernel 3: replay the straight-through chain from stored indices; writes
// quantized + commit_loss. Bit-identical op order to the reference. (R3-proven)
__global__ __launch_bounds__(256) void rvq_replay(const float* __restrict__ z,
                                                  const float* __restrict__ cb,
                                                  float* __restrict__ out) {
    const int p = blockIdx.x * 256 + threadIdx.x;

    float r[RVQ_D], oacc[RVQ_D];
    {
        const float4* zp = (const float4*)(z + (long)p * RVQ_D);
#pragma unroll
        for (int w = 0; w < 8; ++w) {
            const float4 v = zp[w];
            r[w * 4 + 0] = v.x; r[w * 4 + 1] = v.y;
            r[w * 4 + 2] = v.z; r[w * 4 + 3] = v.w;
        }
    }
#pragma unroll
    for (int d = 0; d < RVQ_D; ++d) oacc[d] = 0.0f;

#pragma unroll 1
    for (int q = 0; q < RVQ_Q; ++q) {
        const int idx = (int)out[IDX_OFF + (long)p * RVQ_Q + q];
        const float4* cwb = (const float4*)(cb + ((long)q * RVQ_C + idx) * RVQ_D);
        float cwv[RVQ_D];
#pragma unroll
        for (int w = 0; w < 8; ++w) {
            const float4 v = cwb[w];
            cwv[w * 4 + 0] = v.x; cwv[w * 4 + 1] = v.y;
            cwv[w * 4 + 2] = v.z; cwv[w * 4 + 3] = v.w;
        }
#pragma unroll
        for (int d = 0; d < RVQ_D; ++d) {
            const float qst = r[d] + (cwv[d] - r[d]);
            oacc[d] += qst;
            r[d] = r[d] - qst;
        }
    }

    float4* qo = (float4*)(out + (long)p * RVQ_D);
#pragma unroll
    for (int w = 0; w < 8; ++w) {
        float4 v;
        v.x = oacc[w * 4 + 0]; v.y = oacc[w * 4 + 1];
        v.z = oacc[w * 4 + 2]; v.w = oacc[w * 4 + 3];
        qo[w] = v;
    }

    if (p < RVQ_Q) out[LOSS_OFF + p] = 0.0f;
}

// ---------------------------------------------------------------------------
extern "C" void kernel_launch(void* const* d_in, const int* in_sizes, int n_in,
                              void* d_out, int out_size, void* d_ws, size_t ws_size,
                              hipStream_t stream) {
    const float* z  = (const float*)d_in[0];
    const float* cb = (const float*)d_in[1];
    float* out  = (float*)d_out;
    float* cbn  = (float*)d_ws;          // Q*C floats = 20 KiB scratch
    float* rbuf = out;                   // residual lives in quantized region;
                                         // replay overwrites it at the end
    float* iout = out + IDX_OFF;

    rvq_cb_norms<<<(RVQ_Q * RVQ_C + 255) / 256, 256, 0, stream>>>(cb, cbn);
    for (int q = 0; q < RVQ_Q; ++q)
        rvq_stage<<<NWAVES, 64, 0, stream>>>(q == 0 ? z : rbuf, rbuf, cb, cbn, iout, q);
    rvq_replay<<<NPTS / 256, 256, 0, stream>>>(z, cb, out);
}

// Round 7
// 1625.761 us; speedup vs baseline: 2.1317x; 2.1317x over previous
//
#include <hip/hip_runtime.h>

// Residual VQ on MI355X (gfx950).
// z: [8, 32768, 32] f32; codebooks: [10, 512, 32] f32.
// Outputs (flat f32 in d_out): quantized [B,N,D], indices [B,N,Q] (as float),
// commit_loss [Q] (zeros).
//
// R7 = R6 search structure (4 points/thread, candidate-major eval, all large
// state in named ext_vector_type(32) SSA values, prefetch-1 candidate double
// buffer) with the d_ws/cbn cross-kernel path REMOVED: R6 passed pre-timing
// (absmax 0.0) but diverged on indices across timed replays; the codeword-
// norm buffer in d_ws (poisoned 0xAA between validation and timing) was the
// only added cross-kernel dependency. Here each block recomputes the 512
// norms into LDS at every stage start with the bit-exact numpy tree (pure
// function of cb -> identical on every call). No workspace used at all.
// Distance arithmetic bit-identical to R1 (absmax 0.0 in R1/R3/R4/R5/R6
// pre-timing): 8-accumulator j&7 dot, dist = fma(-2,dot,rr)+cc, strict-<
// ascending-k first-min argmin. Straight-through chain replayed bit-exactly
// by the R3-proven replay kernel (passed post-timing in R3/R4/R5).

#define RVQ_B 8
#define RVQ_N 32768
#define RVQ_D 32
#define RVQ_Q 10
#define RVQ_C 512

static constexpr int  NPTS     = RVQ_B * RVQ_N;             // 262144
static constexpr long IDX_OFF  = (long)NPTS * RVQ_D;        // 8388608
static constexpr long LOSS_OFF = IDX_OFF + (long)NPTS * RVQ_Q;

typedef __attribute__((ext_vector_type(32))) float f32x32;

// ---------------------------------------------------------------------------
// helpers (all constant-indexed -> pure SSA, no arrays survive to regalloc)
__device__ __forceinline__ float dot_self(const f32x32& v) {
    float a[8];
#pragma unroll
    for (int j = 0; j < 8; ++j) a[j] = v[j] * v[j];
#pragma unroll
    for (int j = 8; j < RVQ_D; ++j) a[j & 7] = fmaf(v[j], v[j], a[j & 7]);
    return ((a[0] + a[1]) + (a[2] + a[3])) + ((a[4] + a[5]) + (a[6] + a[7]));
}

__device__ __forceinline__ void eval1(const f32x32& r, const f32x32& c,
                                      float rr, float cc, int k,
                                      float& best, int& bidx) {
    float a[8];
#pragma unroll
    for (int j = 0; j < 8; ++j) a[j] = r[j] * c[j];
#pragma unroll
    for (int j = 8; j < RVQ_D; ++j) a[j & 7] = fmaf(r[j], c[j], a[j & 7]);
    const float dot = ((a[0] + a[1]) + (a[2] + a[3])) + ((a[4] + a[5]) + (a[6] + a[7]));
    const float dist = fmaf(-2.0f, dot, rr) + cc;
    if (dist < best) { best = dist; bidx = k; }   // ascending-k strict-< = first-min
}

// bit-exact straight-through residual update: qst = r + (c - r); r' = r - qst
__device__ __forceinline__ f32x32 st_update(const f32x32& r, const f32x32& g) {
    const f32x32 t   = g - r;
    const f32x32 qst = r + t;
    return r - qst;
}

// ---------------------------------------------------------------------------
// Kernel 1: argmin search, 4 points per thread, all 10 stages in-register.
// Codeword norms recomputed into LDS per block per stage (no workspace).
__global__ __launch_bounds__(256, 1) void rvq_search(const float* __restrict__ z,
                                                     const float* __restrict__ cb,
                                                     float* __restrict__ out) {
    __shared__ float snorm[RVQ_C];

    const int  t  = blockIdx.x * 256 + threadIdx.x;   // 65536 threads
    const long p0 = (long)t * 4;

    const f32x32* zv = (const f32x32*)(z + p0 * RVQ_D);
    f32x32 r0 = zv[0], r1 = zv[1], r2 = zv[2], r3 = zv[3];

#pragma unroll 1
    for (int q = 0; q < RVQ_Q; ++q) {
        const f32x32* cv = (const f32x32*)(cb + (long)q * RVQ_C * RVQ_D);

        // ---- stage norms -> LDS (bit-exact numpy tree, pure function of cb)
        if (q > 0) __syncthreads();      // protect previous stage's snorm reads
#pragma unroll
        for (int n = 0; n < 2; ++n) {
            const int ci = threadIdx.x + n * 256;
            const f32x32 c = cv[ci];
            snorm[ci] = dot_self(c);
        }
        __syncthreads();

        const float rr0 = dot_self(r0), rr1 = dot_self(r1);
        const float rr2 = dot_self(r2), rr3 = dot_self(r3);

        float best0 = __builtin_inff(), best1 = __builtin_inff();
        float best2 = __builtin_inff(), best3 = __builtin_inff();
        int b0 = 0, b1 = 0, b2 = 0, b3 = 0;

        f32x32 cA = cv[0];

#pragma unroll 1
        for (int k = 0; k < RVQ_C - 2; k += 2) {
            const f32x32 cB  = cv[k + 1];          // prefetch k+1
            const float  ccA = snorm[k], ccB = snorm[k + 1];
            eval1(r0, cA, rr0, ccA, k, best0, b0);
            eval1(r1, cA, rr1, ccA, k, best1, b1);
            eval1(r2, cA, rr2, ccA, k, best2, b2);
            eval1(r3, cA, rr3, ccA, k, best3, b3);
            cA = cv[k + 2];                        // prefetch k+2 (unconditional)
            eval1(r0, cB, rr0, ccB, k + 1, best0, b0);
            eval1(r1, cB, rr1, ccB, k + 1, best1, b1);
            eval1(r2, cB, rr2, ccB, k + 1, best2, b2);
            eval1(r3, cB, rr3, ccB, k + 1, best3, b3);
        }
        {   // tail: k = 510, 511 (cA holds cv[510])
            const f32x32 cB  = cv[RVQ_C - 1];
            const float  ccA = snorm[RVQ_C - 2], ccB = snorm[RVQ_C - 1];
            eval1(r0, cA, rr0, ccA, RVQ_C - 2, best0, b0);
            eval1(r1, cA, rr1, ccA, RVQ_C - 2, best1, b1);
            eval1(r2, cA, rr2, ccA, RVQ_C - 2, best2, b2);
            eval1(r3, cA, rr3, ccA, RVQ_C - 2, best3, b3);
            eval1(r0, cB, rr0, ccB, RVQ_C - 1, best0, b0);
            eval1(r1, cB, rr1, ccB, RVQ_C - 1, best1, b1);
            eval1(r2, cB, rr2, ccB, RVQ_C - 1, best2, b2);
            eval1(r3, cB, rr3, ccB, RVQ_C - 1, best3, b3);
        }

        // indices (as float, layout [B,N,Q])
        out[IDX_OFF + (p0 + 0) * RVQ_Q + q] = (float)b0;
        out[IDX_OFF + (p0 + 1) * RVQ_Q + q] = (float)b1;
        out[IDX_OFF + (p0 + 2) * RVQ_Q + q] = (float)b2;
        out[IDX_OFF + (p0 + 3) * RVQ_Q + q] = (float)b3;

        // gather chosen codewords (independent -> overlapped latencies)
        const f32x32 g0 = cv[b0];
        const f32x32 g1 = cv[b1];
        const f32x32 g2 = cv[b2];
        const f32x32 g3 = cv[b3];

        r0 = st_update(r0, g0);
        r1 = st_update(r1, g1);
        r2 = st_update(r2, g2);
        r3 = st_update(r3, g3);
    }
}

// ---------------------------------------------------------------------------
// Kernel 2: replay the straight-through chain from stored indices; writes
// quantized + commit_loss. Bit-identical op order to the reference.
// (Proven pre+post-timing in R3/R4/R5.)
__global__ __launch_bounds__(256) void rvq_replay(const float* __restrict__ z,
                                                  const float* __restrict__ cb,
                                                  float* __restrict__ out) {
    const int p = blockIdx.x * 256 + threadIdx.x;

    float r[RVQ_D], oacc[RVQ_D];
    {
        const float4* zp = (const float4*)(z + (long)p * RVQ_D);
#pragma unroll
        for (int w = 0; w < 8; ++w) {
            const float4 v = zp[w];
            r[w * 4 + 0] = v.x; r[w * 4 + 1] = v.y;
            r[w * 4 + 2] = v.z; r[w * 4 + 3] = v.w;
        }
    }
#pragma unroll
    for (int d = 0; d < RVQ_D; ++d) oacc[d] = 0.0f;

#pragma unroll 1
    for (int q = 0; q < RVQ_Q; ++q) {
        const int idx = (int)out[IDX_OFF + (long)p * RVQ_Q + q];
        const float4* cwb = (const float4*)(cb + ((long)q * RVQ_C + idx) * RVQ_D);
        float cwv[RVQ_D];
#pragma unroll
        for (int w = 0; w < 8; ++w) {
            const float4 v = cwb[w];
            cwv[w * 4 + 0] = v.x; cwv[w * 4 + 1] = v.y;
            cwv[w * 4 + 2] = v.z; cwv[w * 4 + 3] = v.w;
        }
#pragma unroll
        for (int d = 0; d < RVQ_D; ++d) {
            const float qst = r[d] + (cwv[d] - r[d]);
            oacc[d] += qst;
            r[d] = r[d] - qst;
        }
    }

    float4* qo = (float4*)(out + (long)p * RVQ_D);
#pragma unroll
    for (int w = 0; w < 8; ++w) {
        float4 v;
        v.x = oacc[w * 4 + 0]; v.y = oacc[w * 4 + 1];
        v.z = oacc[w * 4 + 2]; v.w = oacc[w * 4 + 3];
        qo[w] = v;
    }

    if (p < RVQ_Q) out[LOSS_OFF + p] = 0.0f;
}

// ---------------------------------------------------------------------------
extern "C" void kernel_launch(void* const* d_in, const int* in_sizes, int n_in,
                              void* d_out, int out_size, void* d_ws, size_t ws_size,
                              hipStream_t stream) {
    const float* z  = (const float*)d_in[0];
    const float* cb = (const float*)d_in[1];
    float* out = (float*)d_out;
    (void)d_ws; (void)ws_size;  // no workspace used (R6 post-timing suspect)

    rvq_search<<<NPTS / 4 / 256, 256, 0, stream>>>(z, cb, out);
    rvq_replay<<<NPTS / 256, 256, 0, stream>>>(z, cb, out);
}

// Round 8
// 1406.999 us; speedup vs baseline: 2.4631x; 1.1555x over previous
//
#include <hip/hip_runtime.h>

// Residual VQ on MI355X (gfx950).
// z: [8, 32768, 32] f32; codebooks: [10, 512, 32] f32.
// Outputs (flat f32 in d_out): quantized [B,N,D], indices [B,N,Q] (as float),
// commit_loss [Q] (zeros).
//
// R8 = R7 (4 points/thread, f32x32 SSA state, candidate-major eval,
// no-workspace, replay kernel) with the candidate stream moved from L2 to
// LDS: R7 showed ~940 stall cyc/iter (VALUBusy 51%, 1 wave/SIMD) because
// the compiler shortened the cA/cB live ranges and exposed ~2 L2 latencies
// per iteration. Each half-pass stages 256 codewords (32 KB) + norms (1 KB)
// into LDS with coalesced float4 loads; candidate reads are same-address
// broadcast ds_read_b128 (conflict-free, ~64-120 cyc latency vs ~225 L2).
// Eval ratio per candidate per CU: 352 VALU-cyc vs 256 LDS-bus-cyc ->
// VALU-bound. Ascending-k strict-< first-min preserved across halves.
// Distance arithmetic bit-identical to R1 (absmax 0.0 pre+post in R7):
// 8-accumulator j&7 dot, dist = fma(-2,dot,rr)+cc. Straight-through chain
// replayed bit-exactly by the proven replay kernel.

#define RVQ_B 8
#define RVQ_N 32768
#define RVQ_D 32
#define RVQ_Q 10
#define RVQ_C 512

static constexpr int  NPTS     = RVQ_B * RVQ_N;             // 262144
static constexpr long IDX_OFF  = (long)NPTS * RVQ_D;        // 8388608
static constexpr long LOSS_OFF = IDX_OFF + (long)NPTS * RVQ_Q;
static constexpr int  HALF     = RVQ_C / 2;                 // 256 codewords

typedef __attribute__((ext_vector_type(32))) float f32x32;

// ---------------------------------------------------------------------------
// helpers (all constant-indexed -> pure SSA)
__device__ __forceinline__ float dot_self(const f32x32& v) {
    float a[8];
#pragma unroll
    for (int j = 0; j < 8; ++j) a[j] = v[j] * v[j];
#pragma unroll
    for (int j = 8; j < RVQ_D; ++j) a[j & 7] = fmaf(v[j], v[j], a[j & 7]);
    return ((a[0] + a[1]) + (a[2] + a[3])) + ((a[4] + a[5]) + (a[6] + a[7]));
}

__device__ __forceinline__ void eval1(const f32x32& r, const f32x32& c,
                                      float rr, float cc, int k,
                                      float& best, int& bidx) {
    float a[8];
#pragma unroll
    for (int j = 0; j < 8; ++j) a[j] = r[j] * c[j];
#pragma unroll
    for (int j = 8; j < RVQ_D; ++j) a[j & 7] = fmaf(r[j], c[j], a[j & 7]);
    const float dot = ((a[0] + a[1]) + (a[2] + a[3])) + ((a[4] + a[5]) + (a[6] + a[7]));
    const float dist = fmaf(-2.0f, dot, rr) + cc;
    if (dist < best) { best = dist; bidx = k; }   // ascending-k strict-< = first-min
}

// bit-exact straight-through residual update: qst = r + (c - r); r' = r - qst
__device__ __forceinline__ f32x32 st_update(const f32x32& r, const f32x32& g) {
    const f32x32 t   = g - r;
    const f32x32 qst = r + t;
    return r - qst;
}

// ---------------------------------------------------------------------------
// Kernel 1: argmin search, 4 points/thread, half-codebook staged in LDS.
__global__ __launch_bounds__(256, 1) void rvq_search(const float* __restrict__ z,
                                                     const float* __restrict__ cb,
                                                     float* __restrict__ out) {
    __shared__ __align__(128) float scb[HALF * RVQ_D];   // 32 KB
    __shared__ float snorm[HALF];                        // 1 KB

    const int  t  = blockIdx.x * 256 + threadIdx.x;   // 65536 threads
    const long p0 = (long)t * 4;

    const f32x32* zv = (const f32x32*)(z + p0 * RVQ_D);
    f32x32 r0 = zv[0], r1 = zv[1], r2 = zv[2], r3 = zv[3];

#pragma unroll 1
    for (int q = 0; q < RVQ_Q; ++q) {
        const f32x32* cv   = (const f32x32*)(cb + (long)q * RVQ_C * RVQ_D);
        const float4* cbq4 = (const float4*)(cb + (long)q * RVQ_C * RVQ_D);

        const float rr0 = dot_self(r0), rr1 = dot_self(r1);
        const float rr2 = dot_self(r2), rr3 = dot_self(r3);

        float best0 = __builtin_inff(), best1 = __builtin_inff();
        float best2 = __builtin_inff(), best3 = __builtin_inff();
        int b0 = 0, b1 = 0, b2 = 0, b3 = 0;

#pragma unroll 1
        for (int h = 0; h < 2; ++h) {
            __syncthreads();   // prior half/stage reads complete before overwrite
            // ---- stage 256 codewords -> LDS (coalesced float4, stride-1 writes)
#pragma unroll
            for (int i = 0; i < 8; ++i) {
                const int idx = threadIdx.x + 256 * i;   // 2048 float4 = 32 KB
                ((float4*)scb)[idx] = cbq4[h * (HALF * 8) + idx];
            }
            // ---- norms (bit-exact numpy tree, pure function of cb)
            snorm[threadIdx.x] = dot_self(cv[h * HALF + threadIdx.x]);
            __syncthreads();

            const f32x32* sv = (const f32x32*)scb;
            const int kg0 = h * HALF;

            f32x32 cA = sv[0];
#pragma unroll 1
            for (int k = 0; k < HALF - 2; k += 2) {
                const f32x32 cB  = sv[k + 1];           // prefetch k+1 (LDS)
                const float  ccA = snorm[k], ccB = snorm[k + 1];
                eval1(r0, cA, rr0, ccA, kg0 + k, best0, b0);
                eval1(r1, cA, rr1, ccA, kg0 + k, best1, b1);
                eval1(r2, cA, rr2, ccA, kg0 + k, best2, b2);
                eval1(r3, cA, rr3, ccA, kg0 + k, best3, b3);
                cA = sv[k + 2];                         // prefetch k+2 (LDS)
                eval1(r0, cB, rr0, ccB, kg0 + k + 1, best0, b0);
                eval1(r1, cB, rr1, ccB, kg0 + k + 1, best1, b1);
                eval1(r2, cB, rr2, ccB, kg0 + k + 1, best2, b2);
                eval1(r3, cB, rr3, ccB, kg0 + k + 1, best3, b3);
            }
            {   // tail: k = HALF-2, HALF-1 (cA holds sv[HALF-2])
                const f32x32 cB  = sv[HALF - 1];
                const float  ccA = snorm[HALF - 2], ccB = snorm[HALF - 1];
                eval1(r0, cA, rr0, ccA, kg0 + HALF - 2, best0, b0);
                eval1(r1, cA, rr1, ccA, kg0 + HALF - 2, best1, b1);
                eval1(r2, cA, rr2, ccA, kg0 + HALF - 2, best2, b2);
                eval1(r3, cA, rr3, ccA, kg0 + HALF - 2, best3, b3);
                eval1(r0, cB, rr0, ccB, kg0 + HALF - 1, best0, b0);
                eval1(r1, cB, rr1, ccB, kg0 + HALF - 1, best1, b1);
                eval1(r2, cB, rr2, ccB, kg0 + HALF - 1, best2, b2);
                eval1(r3, cB, rr3, ccB, kg0 + HALF - 1, best3, b3);
            }
        }

        // indices (as float, layout [B,N,Q])
        out[IDX_OFF + (p0 + 0) * RVQ_Q + q] = (float)b0;
        out[IDX_OFF + (p0 + 1) * RVQ_Q + q] = (float)b1;
        out[IDX_OFF + (p0 + 2) * RVQ_Q + q] = (float)b2;
        out[IDX_OFF + (p0 + 3) * RVQ_Q + q] = (float)b3;

        // gather chosen codewords from global (R7-proven), update residuals
        const f32x32 g0 = cv[b0];
        const f32x32 g1 = cv[b1];
        const f32x32 g2 = cv[b2];
        const f32x32 g3 = cv[b3];

        r0 = st_update(r0, g0);
        r1 = st_update(r1, g1);
        r2 = st_update(r2, g2);
        r3 = st_update(r3, g3);
    }
}

// ---------------------------------------------------------------------------
// Kernel 2: replay the straight-through chain from stored indices; writes
// quantized + commit_loss. Bit-identical op order to the reference.
// (Proven pre+post-timing in R3/R4/R5/R7.)
__global__ __launch_bounds__(256) void rvq_replay(const float* __restrict__ z,
                                                  const float* __restrict__ cb,
                                                  float* __restrict__ out) {
    const int p = blockIdx.x * 256 + threadIdx.x;

    float r[RVQ_D], oacc[RVQ_D];
    {
        const float4* zp = (const float4*)(z + (long)p * RVQ_D);
#pragma unroll
        for (int w = 0; w < 8; ++w) {
            const float4 v = zp[w];
            r[w * 4 + 0] = v.x; r[w * 4 + 1] = v.y;
            r[w * 4 + 2] = v.z; r[w * 4 + 3] = v.w;
        }
    }
#pragma unroll
    for (int d = 0; d < RVQ_D; ++d) oacc[d] = 0.0f;

#pragma unroll 1
    for (int q = 0; q < RVQ_Q; ++q) {
        const int idx = (int)out[IDX_OFF + (long)p * RVQ_Q + q];
        const float4* cwb = (const float4*)(cb + ((long)q * RVQ_C + idx) * RVQ_D);
        float cwv[RVQ_D];
#pragma unroll
        for (int w = 0; w < 8; ++w) {
            const float4 v = cwb[w];
            cwv[w * 4 + 0] = v.x; cwv[w * 4 + 1] = v.y;
            cwv[w * 4 + 2] = v.z; cwv[w * 4 + 3] = v.w;
        }
#pragma unroll
        for (int d = 0; d < RVQ_D; ++d) {
            const float qst = r[d] + (cwv[d] - r[d]);
            oacc[d] += qst;
            r[d] = r[d] - qst;
        }
    }

    float4* qo = (float4*)(out + (long)p * RVQ_D);
#pragma unroll
    for (int w = 0; w < 8; ++w) {
        float4 v;
        v.x = oacc[w * 4 + 0]; v.y = oacc[w * 4 + 1];
        v.z = oacc[w * 4 + 2]; v.w = oacc[w * 4 + 3];
        qo[w] = v;
    }

    if (p < RVQ_Q) out[LOSS_OFF + p] = 0.0f;
}

// ---------------------------------------------------------------------------
extern "C" void kernel_launch(void* const* d_in, const int* in_sizes, int n_in,
                              void* d_out, int out_size, void* d_ws, size_t ws_size,
                              hipStream_t stream) {
    const float* z  = (const float*)d_in[0];
    const float* cb = (const float*)d_in[1];
    float* out = (float*)d_out;
    (void)d_ws; (void)ws_size;  // no workspace (R6 post-timing lesson)

    rvq_search<<<NPTS / 4 / 256, 256, 0, stream>>>(z, cb, out);
    rvq_replay<<<NPTS / 256, 256, 0, stream>>>(z, cb, out);
}